// Round 1
// baseline (221.635 us; speedup 1.0000x reference)
//
#include <hip/hip_runtime.h>
#include <hip/hip_bf16.h>

// Problem constants (B,N,E,H,D) = (2,2048,1024,16,64)
#define B_ 2
#define N_ 2048
#define E_ 1024
#define H_ 16
#define D_ 64
#define M_ 4096      // B*N
#define HD_ 1024     // H*D
#define NT_ 3072     // 3*H*D

using f32x4  = __attribute__((ext_vector_type(4))) float;
using bf16x8 = __attribute__((ext_vector_type(8))) short;

static __device__ __forceinline__ unsigned short f2bf(float f) {
  union { float f; unsigned u; } v; v.f = f;
  unsigned r = v.u + 0x7FFF + ((v.u >> 16) & 1);   // RNE
  return (unsigned short)(r >> 16);
}

// async global->LDS, 16B per lane. LDS dest = wave-uniform base + lane*16.
static __device__ __forceinline__ void gld16(const void* g, void* l) {
  __builtin_amdgcn_global_load_lds(
      (const __attribute__((address_space(1))) unsigned int*)g,
      (__attribute__((address_space(3))) unsigned int*)l, 16, 0, 0);
}

// ---------------- conversion kernels ----------------

__global__ void k_cvt_x(const float* __restrict__ x, unsigned short* __restrict__ xb) {
  int t = blockIdx.x * 256 + threadIdx.x;          // one float4 per thread
  float4 v = reinterpret_cast<const float4*>(x)[t];
  ushort4 o;
  o.x = f2bf(v.x); o.y = f2bf(v.y); o.z = f2bf(v.z); o.w = f2bf(v.w);
  reinterpret_cast<ushort4*>(xb)[t] = o;
}

// Wqkv rows are interleaved (h, d, kind): rin = h*192 + d*3 + kind.
// Output row r = kind*1024 + h*64 + d.  Q rows (kind==0) pre-scaled by 1/8.
__global__ void k_cvt_wqkv(const float* __restrict__ w, const float* __restrict__ bsrc,
                           unsigned short* __restrict__ wb, float* __restrict__ br) {
  int t = blockIdx.x * 256 + threadIdx.x;
  int r = t >> 8;                 // 0..3071
  int c = (t & 255) * 4;
  int kind = r >> 10, hd = r & 1023;
  int h = hd >> 6, d = hd & 63;
  int rin = h * 192 + d * 3 + kind;
  float s = (kind == 0) ? 0.125f : 1.0f;
  float4 v = *reinterpret_cast<const float4*>(w + (size_t)rin * E_ + c);
  ushort4 o;
  o.x = f2bf(v.x * s); o.y = f2bf(v.y * s); o.z = f2bf(v.z * s); o.w = f2bf(v.w * s);
  *reinterpret_cast<ushort4*>(wb + (size_t)r * E_ + c) = o;
  if (c == 0) br[r] = bsrc[rin] * s;
}

__global__ void k_cvt_wout(const float* __restrict__ w, unsigned short* __restrict__ wb) {
  int t = blockIdx.x * 256 + threadIdx.x;
  int r = t >> 8;
  int c = (t & 255) * 4;
  float4 v = *reinterpret_cast<const float4*>(w + (size_t)r * HD_ + c);
  ushort4 o;
  o.x = f2bf(v.x); o.y = f2bf(v.y); o.z = f2bf(v.z); o.w = f2bf(v.w);
  *reinterpret_cast<ushort4*>(wb + (size_t)r * HD_ + c) = o;
}

// ---------------- GEMM: C[m][n] = sum_k A[m][k]*W[n][k] + bias[n] ----------------
// m97 structure: 128x128 tile, BK=32, 4 waves, each wave 64x64 (4x4 frags of 16x16).
// EPI 0: QKV scatter epilogue (bf16 -> Q[b][h][n][d], K[b][h][n][d], V[b][h][d][n])
// EPI 1: f32 epilogue into out
template <int EPI>
__global__ __launch_bounds__(256, 2) void k_gemm(
    const unsigned short* __restrict__ A,   // [M][K] bf16
    const unsigned short* __restrict__ W,   // [Nt][K] bf16
    const float* __restrict__ bias,         // [Nt]
    unsigned short* __restrict__ Qo, unsigned short* __restrict__ Ko,
    unsigned short* __restrict__ Vo, float* __restrict__ Fo,
    int M, int Nt, int K)
{
  __shared__ unsigned short As[128 * 32];
  __shared__ unsigned short Bs[128 * 32];
  const int t = threadIdx.x;
  const int w = t >> 6, l = t & 63, lg = l >> 4, lr = l & 15;
  const int wm = w >> 1, wn = w & 1;
  const int row0 = blockIdx.x * 128, col0 = blockIdx.y * 128;

  f32x4 acc[4][4] = {};

  for (int k0 = 0; k0 < K; k0 += 32) {
#pragma unroll
    for (int c = 0; c < 2; ++c) {
      int ci = w * 2 + c;
      int eo = ci * 512 + l * 8;            // element offset within 128x32 tile
      int rr = eo >> 5, kk = eo & 31;
      gld16(A + (size_t)(row0 + rr) * K + k0 + kk, (unsigned short*)As + ci * 512);
      gld16(W + (size_t)(col0 + rr) * K + k0 + kk, (unsigned short*)Bs + ci * 512);
    }
    __syncthreads();
    bf16x8 af[4], bf[4];
#pragma unroll
    for (int m = 0; m < 4; ++m)
      af[m] = *reinterpret_cast<const bf16x8*>(&As[(wm * 64 + m * 16 + lr) * 32 + lg * 8]);
#pragma unroll
    for (int n = 0; n < 4; ++n)
      bf[n] = *reinterpret_cast<const bf16x8*>(&Bs[(wn * 64 + n * 16 + lr) * 32 + lg * 8]);
#pragma unroll
    for (int m = 0; m < 4; ++m)
#pragma unroll
      for (int n = 0; n < 4; ++n)
        acc[m][n] = __builtin_amdgcn_mfma_f32_16x16x32_bf16(af[m], bf[n], acc[m][n], 0, 0, 0);
    __syncthreads();
  }

#pragma unroll
  for (int m = 0; m < 4; ++m) {
#pragma unroll
    for (int n = 0; n < 4; ++n) {
      int col = col0 + wn * 64 + n * 16 + lr;
      float bb = bias[col];
#pragma unroll
      for (int rr = 0; rr < 4; ++rr) {
        int ro = row0 + wm * 64 + m * 16 + lg * 4 + rr;
        float val = acc[m][n][rr] + bb;
        if (EPI == 0) {
          int kind = col >> 10, hd = col & 1023, h = hd >> 6, d = hd & 63;
          int bi = ro >> 11, ni = ro & 2047;     // token -> (b, n)
          unsigned short bv = f2bf(val);
          size_t bh = (size_t)(bi * H_ + h);
          if (kind == 0)      Qo[(bh * N_ + ni) * D_ + d] = bv;
          else if (kind == 1) Ko[(bh * N_ + ni) * D_ + d] = bv;
          else                Vo[bh * (size_t)(D_ * N_) + (size_t)d * N_ + ni] = bv;
        } else {
          Fo[(size_t)ro * HD_ + col] = val;
        }
      }
    }
  }
}

// ---------------- flash attention ----------------
// grid: (N/64, B*H). 256 threads = 4 waves; wave w owns q rows [q0+16w, q0+16w+15].
// Q,K: [b][h][n][d] bf16 (Q pre-scaled by 1/8). V: [b][h][d][n] bf16.
// Output: attn_out bf16 [b][n][h][d].
__global__ __launch_bounds__(256, 2) void k_attn(
    const unsigned short* __restrict__ Q,
    const unsigned short* __restrict__ Kg,
    const unsigned short* __restrict__ Vg,
    unsigned short* __restrict__ O)
{
  __shared__ unsigned short Ks[64 * 64];   // [kv][d]
  __shared__ unsigned short Vs[64 * 64];   // [d][kv]
  __shared__ unsigned short Ps[4][16 * 64];
  const int t = threadIdx.x;
  const int w = t >> 6, l = t & 63, lg = l >> 4, lr = l & 15;
  const int q0 = blockIdx.x * 64;
  const int bh = blockIdx.y;

  const unsigned short* Qb = Q + (size_t)bh * (N_ * D_);
  const unsigned short* Kb = Kg + (size_t)bh * (N_ * D_);
  const unsigned short* Vb = Vg + (size_t)bh * (N_ * D_);

  // Q fragments (A-frag: lane holds row lr, k = 32*kk + lg*8 .. +7)
  const int qrow = q0 + w * 16 + lr;
  bf16x8 aq0 = *reinterpret_cast<const bf16x8*>(Qb + (size_t)qrow * D_ + lg * 8);
  bf16x8 aq1 = *reinterpret_cast<const bf16x8*>(Qb + (size_t)qrow * D_ + 32 + lg * 8);

  f32x4 oacc[4] = {};
  float mrun[4], lrun[4];
#pragma unroll
  for (int r = 0; r < 4; ++r) { mrun[r] = -1e30f; lrun[r] = 0.f; }

  for (int kv0 = 0; kv0 <= q0; kv0 += 64) {
    // stage K tile (contiguous rows) and V^T tile
#pragma unroll
    for (int c = 0; c < 2; ++c) {
      int ci = w * 2 + c;
      int eo = ci * 512 + l * 8;
      gld16(Kb + (size_t)kv0 * D_ + eo, (unsigned short*)Ks + ci * 512);
      int d = eo >> 6, kvl = eo & 63;
      gld16(Vb + (size_t)d * N_ + kv0 + kvl, (unsigned short*)Vs + ci * 512);
    }
    __syncthreads();

    // S = Q K^T   (C layout: row = lg*4+r (q), col = lr (kv within ct tile))
    f32x4 s[4];
#pragma unroll
    for (int ct = 0; ct < 4; ++ct) {
      bf16x8 b0 = *reinterpret_cast<const bf16x8*>(&Ks[(ct * 16 + lr) * 64 + lg * 8]);
      bf16x8 b1 = *reinterpret_cast<const bf16x8*>(&Ks[(ct * 16 + lr) * 64 + 32 + lg * 8]);
      f32x4 z = {};
      z = __builtin_amdgcn_mfma_f32_16x16x32_bf16(aq0, b0, z, 0, 0, 0);
      z = __builtin_amdgcn_mfma_f32_16x16x32_bf16(aq1, b1, z, 0, 0, 0);
      s[ct] = z;
    }

    if (kv0 == q0) {   // diagonal tile: causal mask
#pragma unroll
      for (int ct = 0; ct < 4; ++ct)
#pragma unroll
        for (int r = 0; r < 4; ++r) {
          int col = kv0 + ct * 16 + lr;
          int row = q0 + w * 16 + lg * 4 + r;
          if (col > row) s[ct][r] = -1e30f;
        }
    }

    // online softmax (row state replicated across the 16 col-lanes)
    float p[4][4], corr[4];
#pragma unroll
    for (int r = 0; r < 4; ++r) {
      float mx = fmaxf(fmaxf(s[0][r], s[1][r]), fmaxf(s[2][r], s[3][r]));
      mx = fmaxf(mx, __shfl_xor(mx, 1));
      mx = fmaxf(mx, __shfl_xor(mx, 2));
      mx = fmaxf(mx, __shfl_xor(mx, 4));
      mx = fmaxf(mx, __shfl_xor(mx, 8));
      float mnew = fmaxf(mrun[r], mx);
      corr[r] = __expf(mrun[r] - mnew);
      float ps = 0.f;
#pragma unroll
      for (int ct = 0; ct < 4; ++ct) {
        float pv = __expf(s[ct][r] - mnew);
        p[ct][r] = pv; ps += pv;
      }
      ps += __shfl_xor(ps, 1);
      ps += __shfl_xor(ps, 2);
      ps += __shfl_xor(ps, 4);
      ps += __shfl_xor(ps, 8);
      lrun[r] = lrun[r] * corr[r] + ps;
      mrun[r] = mnew;
    }
#pragma unroll
    for (int dt = 0; dt < 4; ++dt)
#pragma unroll
      for (int r = 0; r < 4; ++r)
        oacc[dt][r] *= corr[r];

    // P -> LDS (per-wave region), reload as A-frags
#pragma unroll
    for (int ct = 0; ct < 4; ++ct)
#pragma unroll
      for (int r = 0; r < 4; ++r)
        Ps[w][(lg * 4 + r) * 64 + ct * 16 + lr] = f2bf(p[ct][r]);

    bf16x8 pa0 = *reinterpret_cast<const bf16x8*>(&Ps[w][lr * 64 + lg * 8]);
    bf16x8 pa1 = *reinterpret_cast<const bf16x8*>(&Ps[w][lr * 64 + 32 + lg * 8]);
#pragma unroll
    for (int dt = 0; dt < 4; ++dt) {
      bf16x8 v0 = *reinterpret_cast<const bf16x8*>(&Vs[(dt * 16 + lr) * 64 + lg * 8]);
      bf16x8 v1 = *reinterpret_cast<const bf16x8*>(&Vs[(dt * 16 + lr) * 64 + 32 + lg * 8]);
      oacc[dt] = __builtin_amdgcn_mfma_f32_16x16x32_bf16(pa0, v0, oacc[dt], 0, 0, 0);
      oacc[dt] = __builtin_amdgcn_mfma_f32_16x16x32_bf16(pa1, v1, oacc[dt], 0, 0, 0);
    }
    __syncthreads();
  }

  // epilogue: write attn_out [b][n][h][d] bf16
  int bi = bh >> 4, h = bh & 15;
#pragma unroll
  for (int dt = 0; dt < 4; ++dt)
#pragma unroll
    for (int r = 0; r < 4; ++r) {
      int qr = q0 + w * 16 + lg * 4 + r;
      float val = oacc[dt][r] / lrun[r];
      O[((size_t)(bi * N_ + qr) * H_ + h) * D_ + dt * 16 + lr] = f2bf(val);
    }
}

// ---------------- launch ----------------

extern "C" void kernel_launch(void* const* d_in, const int* in_sizes, int n_in,
                              void* d_out, int out_size, void* d_ws, size_t ws_size,
                              hipStream_t stream) {
  const float* x    = (const float*)d_in[0];
  const float* Wqkv = (const float*)d_in[1];
  const float* bqkv = (const float*)d_in[2];
  const float* Wout = (const float*)d_in[3];
  const float* bout = (const float*)d_in[4];
  float* out = (float*)d_out;

  char* ws = (char*)d_ws;
  unsigned short* xb  = (unsigned short*)ws; ws += (size_t)M_ * E_ * 2;       // 8 MB
  unsigned short* wqb = (unsigned short*)ws; ws += (size_t)NT_ * E_ * 2;      // 6 MB
  float*          bqr = (float*)ws;          ws += 16384;                     // 12 KB (+pad)
  unsigned short* wob = (unsigned short*)ws; ws += (size_t)E_ * HD_ * 2;      // 2 MB
  unsigned short* Qb  = (unsigned short*)ws; ws += (size_t)M_ * D_ * H_ * 2;  // 8 MB
  unsigned short* Kb  = (unsigned short*)ws; ws += (size_t)M_ * D_ * H_ * 2;  // 8 MB
  unsigned short* Vb  = (unsigned short*)ws; ws += (size_t)M_ * D_ * H_ * 2;  // 8 MB
  unsigned short* ao  = (unsigned short*)ws; ws += (size_t)M_ * HD_ * 2;      // 8 MB

  k_cvt_x<<<(M_ * E_) / 4 / 256, 256, 0, stream>>>(x, xb);
  k_cvt_wqkv<<<NT_, 256, 0, stream>>>(Wqkv, bqkv, wqb, bqr);
  k_cvt_wout<<<E_, 256, 0, stream>>>(Wout, wob);

  k_gemm<0><<<dim3(M_ / 128, NT_ / 128), 256, 0, stream>>>(
      xb, wqb, bqr, Qb, Kb, Vb, nullptr, M_, NT_, E_);

  k_attn<<<dim3(N_ / 64, B_ * H_), 256, 0, stream>>>(Qb, Kb, Vb, ao);

  k_gemm<1><<<dim3(M_ / 128, HD_ / 128), 256, 0, stream>>>(
      ao, wob, bout, nullptr, nullptr, nullptr, out, M_, HD_, E_);
}

// Round 2
// 199.942 us; speedup vs baseline: 1.1085x; 1.1085x over previous
//
#include <hip/hip_runtime.h>
#include <hip/hip_bf16.h>

// Problem constants (B,N,E,H,D) = (2,2048,1024,16,64)
#define B_ 2
#define N_ 2048
#define E_ 1024
#define H_ 16
#define D_ 64
#define M_ 4096      // B*N
#define HD_ 1024     // H*D
#define NT_ 3072     // 3*H*D

using f32x4  = __attribute__((ext_vector_type(4))) float;
using bf16x8 = __attribute__((ext_vector_type(8))) short;

static __device__ __forceinline__ unsigned short f2bf(float f) {
  union { float f; unsigned u; } v; v.f = f;
  unsigned r = v.u + 0x7FFF + ((v.u >> 16) & 1);   // RNE
  return (unsigned short)(r >> 16);
}

// async global->LDS, 16B per lane. LDS dest = wave-uniform base + lane*16.
static __device__ __forceinline__ void gld16(const void* g, void* l) {
  __builtin_amdgcn_global_load_lds(
      (const __attribute__((address_space(1))) unsigned int*)g,
      (__attribute__((address_space(3))) unsigned int*)l, 16, 0, 0);
}

// ---------------- conversion kernels ----------------

__global__ void k_cvt_x(const float* __restrict__ x, unsigned short* __restrict__ xb) {
  int t = blockIdx.x * 256 + threadIdx.x;          // one float4 per thread
  float4 v = reinterpret_cast<const float4*>(x)[t];
  ushort4 o;
  o.x = f2bf(v.x); o.y = f2bf(v.y); o.z = f2bf(v.z); o.w = f2bf(v.w);
  reinterpret_cast<ushort4*>(xb)[t] = o;
}

// Wqkv rows are interleaved (h, d, kind): rin = h*192 + d*3 + kind.
// Output row r = kind*1024 + h*64 + d.
// Q rows (kind==0) pre-scaled by (1/8)*log2(e) so attention can use exp2.
__global__ void k_cvt_wqkv(const float* __restrict__ w, const float* __restrict__ bsrc,
                           unsigned short* __restrict__ wb, float* __restrict__ br) {
  int t = blockIdx.x * 256 + threadIdx.x;
  int r = t >> 8;                 // 0..3071
  int c = (t & 255) * 4;
  int kind = r >> 10, hd = r & 1023;
  int h = hd >> 6, d = hd & 63;
  int rin = h * 192 + d * 3 + kind;
  float s = (kind == 0) ? 0.125f * 1.4426950408889634f : 1.0f;
  float4 v = *reinterpret_cast<const float4*>(w + (size_t)rin * E_ + c);
  ushort4 o;
  o.x = f2bf(v.x * s); o.y = f2bf(v.y * s); o.z = f2bf(v.z * s); o.w = f2bf(v.w * s);
  *reinterpret_cast<ushort4*>(wb + (size_t)r * E_ + c) = o;
  if (c == 0) br[r] = bsrc[rin] * s;
}

__global__ void k_cvt_wout(const float* __restrict__ w, unsigned short* __restrict__ wb) {
  int t = blockIdx.x * 256 + threadIdx.x;
  int r = t >> 8;
  int c = (t & 255) * 4;
  float4 v = *reinterpret_cast<const float4*>(w + (size_t)r * HD_ + c);
  ushort4 o;
  o.x = f2bf(v.x); o.y = f2bf(v.y); o.z = f2bf(v.z); o.w = f2bf(v.w);
  *reinterpret_cast<ushort4*>(wb + (size_t)r * HD_ + c) = o;
}

// ---------------- GEMM: C[m][n] = sum_k A[m][k]*W[n][k] + bias[n] ----------------
// m97 structure: 128x128 tile, BK=32, 4 waves, each wave 64x64 (4x4 frags of 16x16).
// EPI 0: QKV scatter epilogue (bf16 -> Q[b][h][n][d], K[b][h][n][d], V[b][h][d][n])
// EPI 1: f32 epilogue into out
template <int EPI>
__global__ __launch_bounds__(256, 2) void k_gemm(
    const unsigned short* __restrict__ A,   // [M][K] bf16
    const unsigned short* __restrict__ W,   // [Nt][K] bf16
    const float* __restrict__ bias,         // [Nt]
    unsigned short* __restrict__ Qo, unsigned short* __restrict__ Ko,
    unsigned short* __restrict__ Vo, float* __restrict__ Fo,
    int M, int Nt, int K)
{
  __shared__ unsigned short As[128 * 32];
  __shared__ unsigned short Bs[128 * 32];
  const int t = threadIdx.x;
  const int w = t >> 6, l = t & 63, lg = l >> 4, lr = l & 15;
  const int wm = w >> 1, wn = w & 1;
  const int row0 = blockIdx.x * 128, col0 = blockIdx.y * 128;

  f32x4 acc[4][4] = {};

  for (int k0 = 0; k0 < K; k0 += 32) {
#pragma unroll
    for (int c = 0; c < 2; ++c) {
      int ci = w * 2 + c;
      int eo = ci * 512 + l * 8;            // element offset within 128x32 tile
      int rr = eo >> 5, kk = eo & 31;
      gld16(A + (size_t)(row0 + rr) * K + k0 + kk, (unsigned short*)As + ci * 512);
      gld16(W + (size_t)(col0 + rr) * K + k0 + kk, (unsigned short*)Bs + ci * 512);
    }
    __syncthreads();
    bf16x8 af[4], bf[4];
#pragma unroll
    for (int m = 0; m < 4; ++m)
      af[m] = *reinterpret_cast<const bf16x8*>(&As[(wm * 64 + m * 16 + lr) * 32 + lg * 8]);
#pragma unroll
    for (int n = 0; n < 4; ++n)
      bf[n] = *reinterpret_cast<const bf16x8*>(&Bs[(wn * 64 + n * 16 + lr) * 32 + lg * 8]);
#pragma unroll
    for (int m = 0; m < 4; ++m)
#pragma unroll
      for (int n = 0; n < 4; ++n)
        acc[m][n] = __builtin_amdgcn_mfma_f32_16x16x32_bf16(af[m], bf[n], acc[m][n], 0, 0, 0);
    __syncthreads();
  }

#pragma unroll
  for (int m = 0; m < 4; ++m) {
#pragma unroll
    for (int n = 0; n < 4; ++n) {
      int col = col0 + wn * 64 + n * 16 + lr;
      float bb = bias[col];
#pragma unroll
      for (int rr = 0; rr < 4; ++rr) {
        int ro = row0 + wm * 64 + m * 16 + lg * 4 + rr;
        float val = acc[m][n][rr] + bb;
        if (EPI == 0) {
          int kind = col >> 10, hd = col & 1023, h = hd >> 6, d = hd & 63;
          int bi = ro >> 11, ni = ro & 2047;     // token -> (b, n)
          unsigned short bv = f2bf(val);
          size_t bh = (size_t)(bi * H_ + h);
          if (kind == 0)      Qo[(bh * N_ + ni) * D_ + d] = bv;
          else if (kind == 1) Ko[(bh * N_ + ni) * D_ + d] = bv;
          else                Vo[bh * (size_t)(D_ * N_) + (size_t)d * N_ + ni] = bv;
        } else {
          Fo[(size_t)ro * HD_ + col] = val;
        }
      }
    }
  }
}

// ---------------- flash attention (no-staging, barrier-free) ----------------
// grid: (N/128, B*H). 256 threads = 4 waves; wave w owns q rows [q0+32w, q0+32w+31]
// (two 16-row groups rg=0,1). KV tiles of 64, K/V fragments loaded DIRECTLY from
// global (L2-resident: 512KB per head). Per-wave causal loop bound; zero barriers.
// Q pre-scaled by (1/8)*log2e -> softmax in exp2 domain.
// P goes through a per-wave XOR-swizzled LDS buffer (write row-major, read as A-frag).
__global__ __launch_bounds__(256, 2) void k_attn(
    const unsigned short* __restrict__ Q,
    const unsigned short* __restrict__ Kg,
    const unsigned short* __restrict__ Vg,
    unsigned short* __restrict__ O)
{
  __shared__ unsigned short Ps[4][32 * 64];   // per-wave P tile, 16 KB total
  const int t = threadIdx.x;
  const int w = t >> 6, l = t & 63, lg = l >> 4, lr = l & 15;
  const int qt = gridDim.x - 1 - blockIdx.x;   // heavy q-tiles launch first
  const int q0 = qt * 128;
  const int bh = blockIdx.y;
  const int r0w = q0 + w * 32;                 // first q row owned by this wave
  const int rtop = r0w + 31;                   // last q row owned by this wave

  const unsigned short* Qb = Q  + (size_t)bh * (N_ * D_);
  const unsigned short* Kb = Kg + (size_t)bh * (N_ * D_);
  const unsigned short* Vb = Vg + (size_t)bh * (N_ * D_);   // [d][n]
  char* pw = (char*)&Ps[w][0];

  // Q A-fragments: lane holds row lr (of 16-row group), k = kk*32 + lg*8 ..+7
  bf16x8 aq[2][2];
#pragma unroll
  for (int rg = 0; rg < 2; ++rg)
#pragma unroll
    for (int kk = 0; kk < 2; ++kk)
      aq[rg][kk] = *reinterpret_cast<const bf16x8*>(
          Qb + (size_t)(r0w + rg * 16 + lr) * D_ + kk * 32 + lg * 8);

  f32x4 oacc[2][4] = {};
  float mrun[2][4], lrun[2][4];
#pragma unroll
  for (int rg = 0; rg < 2; ++rg)
#pragma unroll
    for (int r = 0; r < 4; ++r) { mrun[rg][r] = -1e30f; lrun[rg][r] = 0.f; }

  // first K tile (B-frag: lane holds kv-row lr, k = kk*32+lg*8)
  bf16x8 kb[4][2];
#pragma unroll
  for (int ct = 0; ct < 4; ++ct)
#pragma unroll
    for (int kk = 0; kk < 2; ++kk)
      kb[ct][kk] = *reinterpret_cast<const bf16x8*>(
          Kb + (size_t)(ct * 16 + lr) * D_ + kk * 32 + lg * 8);

  for (int kv0 = 0; kv0 <= rtop; kv0 += 64) {
    // ---- S = Q K^T ----
    f32x4 s[2][4];
#pragma unroll
    for (int rg = 0; rg < 2; ++rg)
#pragma unroll
      for (int ct = 0; ct < 4; ++ct) {
        f32x4 z = {};
        z = __builtin_amdgcn_mfma_f32_16x16x32_bf16(aq[rg][0], kb[ct][0], z, 0, 0, 0);
        z = __builtin_amdgcn_mfma_f32_16x16x32_bf16(aq[rg][1], kb[ct][1], z, 0, 0, 0);
        s[rg][ct] = z;
      }

    // ---- prefetch next K tile (hides L2 latency under softmax + PV) ----
    if (kv0 + 64 <= rtop) {
      const unsigned short* kp = Kb + (size_t)(kv0 + 64) * D_;
#pragma unroll
      for (int ct = 0; ct < 4; ++ct)
#pragma unroll
        for (int kk = 0; kk < 2; ++kk)
          kb[ct][kk] = *reinterpret_cast<const bf16x8*>(
              kp + (size_t)(ct * 16 + lr) * D_ + kk * 32 + lg * 8);
    }

    // ---- V B-fragments for current tile (independent of softmax -> overlaps) ----
    bf16x8 vb[4][2];
#pragma unroll
    for (int dt = 0; dt < 4; ++dt)
#pragma unroll
      for (int kk = 0; kk < 2; ++kk)
        vb[dt][kk] = *reinterpret_cast<const bf16x8*>(
            Vb + (size_t)(dt * 16 + lr) * N_ + kv0 + kk * 32 + lg * 8);

    // ---- causal mask (only tiles intersecting the diagonal) ----
    if (kv0 + 63 > r0w) {
#pragma unroll
      for (int rg = 0; rg < 2; ++rg)
#pragma unroll
        for (int ct = 0; ct < 4; ++ct)
#pragma unroll
          for (int r = 0; r < 4; ++r) {
            int col = kv0 + ct * 16 + lr;
            int row = r0w + rg * 16 + lg * 4 + r;
            if (col > row) s[rg][ct][r] = -1e30f;
          }
    }

    // ---- online softmax (exp2 domain; row state replicated across 16 lr lanes) ----
#pragma unroll
    for (int rg = 0; rg < 2; ++rg) {
      float corr[4];
#pragma unroll
      for (int r = 0; r < 4; ++r) {
        float mx = fmaxf(fmaxf(s[rg][0][r], s[rg][1][r]), fmaxf(s[rg][2][r], s[rg][3][r]));
        mx = fmaxf(mx, __shfl_xor(mx, 1));
        mx = fmaxf(mx, __shfl_xor(mx, 2));
        mx = fmaxf(mx, __shfl_xor(mx, 4));
        mx = fmaxf(mx, __shfl_xor(mx, 8));
        float mnew = fmaxf(mrun[rg][r], mx);
        corr[r] = exp2f(mrun[rg][r] - mnew);
        float ps = 0.f;
#pragma unroll
        for (int ct = 0; ct < 4; ++ct) {
          float pv = exp2f(s[rg][ct][r] - mnew);
          s[rg][ct][r] = pv; ps += pv;
        }
        ps += __shfl_xor(ps, 1);
        ps += __shfl_xor(ps, 2);
        ps += __shfl_xor(ps, 4);
        ps += __shfl_xor(ps, 8);
        lrun[rg][r] = lrun[rg][r] * corr[r] + ps;
        mrun[rg][r] = mnew;
      }
      // P -> per-wave LDS, XOR-swizzled (byte ^= (row&7)<<4)
#pragma unroll
      for (int ct = 0; ct < 4; ++ct)
#pragma unroll
        for (int r = 0; r < 4; ++r) {
          int row = rg * 16 + lg * 4 + r;
          int bo = (row * 128 + (ct * 16 + lr) * 2) ^ ((row & 7) << 4);
          *(unsigned short*)(pw + bo) = f2bf(s[rg][ct][r]);
        }
      // rescale O accumulator
#pragma unroll
      for (int dt = 0; dt < 4; ++dt)
#pragma unroll
        for (int r = 0; r < 4; ++r)
          oacc[rg][dt][r] *= corr[r];
    }

    // ---- PV: read P as A-frags (same swizzle), accumulate ----
#pragma unroll
    for (int rg = 0; rg < 2; ++rg) {
      bf16x8 pa[2];
#pragma unroll
      for (int kk = 0; kk < 2; ++kk) {
        int row = rg * 16 + lr;
        int bo = (row * 128 + (kk * 32 + lg * 8) * 2) ^ ((row & 7) << 4);
        pa[kk] = *reinterpret_cast<const bf16x8*>(pw + bo);
      }
#pragma unroll
      for (int dt = 0; dt < 4; ++dt) {
        oacc[rg][dt] = __builtin_amdgcn_mfma_f32_16x16x32_bf16(pa[0], vb[dt][0], oacc[rg][dt], 0, 0, 0);
        oacc[rg][dt] = __builtin_amdgcn_mfma_f32_16x16x32_bf16(pa[1], vb[dt][1], oacc[rg][dt], 0, 0, 0);
      }
    }
  }

  // ---- epilogue: attn_out [b][n][h][d] bf16 ----
  int bi = bh >> 4, h = bh & 15;
#pragma unroll
  for (int rg = 0; rg < 2; ++rg)
#pragma unroll
    for (int dt = 0; dt < 4; ++dt)
#pragma unroll
      for (int r = 0; r < 4; ++r) {
        int qr = r0w + rg * 16 + lg * 4 + r;
        float val = oacc[rg][dt][r] / lrun[rg][r];
        O[((size_t)(bi * N_ + qr) * H_ + h) * D_ + dt * 16 + lr] = f2bf(val);
      }
}

// ---------------- launch ----------------

extern "C" void kernel_launch(void* const* d_in, const int* in_sizes, int n_in,
                              void* d_out, int out_size, void* d_ws, size_t ws_size,
                              hipStream_t stream) {
  const float* x    = (const float*)d_in[0];
  const float* Wqkv = (const float*)d_in[1];
  const float* bqkv = (const float*)d_in[2];
  const float* Wout = (const float*)d_in[3];
  const float* bout = (const float*)d_in[4];
  float* out = (float*)d_out;

  char* ws = (char*)d_ws;
  unsigned short* xb  = (unsigned short*)ws; ws += (size_t)M_ * E_ * 2;       // 8 MB
  unsigned short* wqb = (unsigned short*)ws; ws += (size_t)NT_ * E_ * 2;      // 6 MB
  float*          bqr = (float*)ws;          ws += 16384;                     // 12 KB (+pad)
  unsigned short* wob = (unsigned short*)ws; ws += (size_t)E_ * HD_ * 2;      // 2 MB
  unsigned short* Qb  = (unsigned short*)ws; ws += (size_t)M_ * D_ * H_ * 2;  // 8 MB
  unsigned short* Kb  = (unsigned short*)ws; ws += (size_t)M_ * D_ * H_ * 2;  // 8 MB
  unsigned short* Vb  = (unsigned short*)ws; ws += (size_t)M_ * D_ * H_ * 2;  // 8 MB
  unsigned short* ao  = (unsigned short*)ws; ws += (size_t)M_ * HD_ * 2;      // 8 MB

  k_cvt_x<<<(M_ * E_) / 4 / 256, 256, 0, stream>>>(x, xb);
  k_cvt_wqkv<<<NT_, 256, 0, stream>>>(Wqkv, bqkv, wqb, bqr);
  k_cvt_wout<<<E_, 256, 0, stream>>>(Wout, wob);

  k_gemm<0><<<dim3(M_ / 128, NT_ / 128), 256, 0, stream>>>(
      xb, wqb, bqr, Qb, Kb, Vb, nullptr, M_, NT_, E_);

  k_attn<<<dim3(N_ / 128, B_ * H_), 256, 0, stream>>>(Qb, Kb, Vb, ao);

  k_gemm<1><<<dim3(M_ / 128, HD_ / 128), 256, 0, stream>>>(
      ao, wob, bout, nullptr, nullptr, nullptr, out, M_, HD_, E_);
}

// Round 3
// 158.097 us; speedup vs baseline: 1.4019x; 1.2647x over previous
//
#include <hip/hip_runtime.h>
#include <hip/hip_bf16.h>

// Problem constants (B,N,E,H,D) = (2,2048,1024,16,64)
#define B_ 2
#define N_ 2048
#define E_ 1024
#define H_ 16
#define D_ 64
#define M_ 4096      // B*N
#define HD_ 1024     // H*D
#define NT_ 3072     // 3*H*D

using f32x4  = __attribute__((ext_vector_type(4))) float;
using bf16x8 = __attribute__((ext_vector_type(8))) short;

static __device__ __forceinline__ unsigned short f2bf(float f) {
  union { float f; unsigned u; } v; v.f = f;
  unsigned r = v.u + 0x7FFF + ((v.u >> 16) & 1);   // RNE
  return (unsigned short)(r >> 16);
}
static __device__ __forceinline__ float bf2f(short s) {
  union { unsigned u; float f; } v; v.u = ((unsigned)(unsigned short)s) << 16; return v.f;
}

// async global->LDS, 16B per lane. LDS dest = wave-uniform base + lane*16.
static __device__ __forceinline__ void gld16(const void* g, void* l) {
  __builtin_amdgcn_global_load_lds(
      (const __attribute__((address_space(1))) unsigned int*)g,
      (__attribute__((address_space(3))) unsigned int*)l, 16, 0, 0);
}

// ---------------- conversion kernels ----------------

__global__ void k_cvt_x(const float* __restrict__ x, unsigned short* __restrict__ xb) {
  int t = blockIdx.x * 256 + threadIdx.x;          // one float4 per thread
  float4 v = reinterpret_cast<const float4*>(x)[t];
  ushort4 o;
  o.x = f2bf(v.x); o.y = f2bf(v.y); o.z = f2bf(v.z); o.w = f2bf(v.w);
  reinterpret_cast<ushort4*>(xb)[t] = o;
}

// Wqkv rows are interleaved (h, d, kind): rin = h*192 + d*3 + kind.
// Output row r = kind*1024 + h*64 + d.
// Q rows (kind==0) pre-scaled by (1/8)*log2(e) so attention can use exp2.
__global__ void k_cvt_wqkv(const float* __restrict__ w, const float* __restrict__ bsrc,
                           unsigned short* __restrict__ wb, float* __restrict__ br) {
  int t = blockIdx.x * 256 + threadIdx.x;
  int r = t >> 8;                 // 0..3071
  int c = (t & 255) * 4;
  int kind = r >> 10, hd = r & 1023;
  int h = hd >> 6, d = hd & 63;
  int rin = h * 192 + d * 3 + kind;
  float s = (kind == 0) ? 0.125f * 1.4426950408889634f : 1.0f;
  float4 v = *reinterpret_cast<const float4*>(w + (size_t)rin * E_ + c);
  ushort4 o;
  o.x = f2bf(v.x * s); o.y = f2bf(v.y * s); o.z = f2bf(v.z * s); o.w = f2bf(v.w * s);
  *reinterpret_cast<ushort4*>(wb + (size_t)r * E_ + c) = o;
  if (c == 0) br[r] = bsrc[rin] * s;
}

__global__ void k_cvt_wout(const float* __restrict__ w, unsigned short* __restrict__ wb) {
  int t = blockIdx.x * 256 + threadIdx.x;
  int r = t >> 8;
  int c = (t & 255) * 4;
  float4 v = *reinterpret_cast<const float4*>(w + (size_t)r * HD_ + c);
  ushort4 o;
  o.x = f2bf(v.x); o.y = f2bf(v.y); o.z = f2bf(v.z); o.w = f2bf(v.w);
  *reinterpret_cast<ushort4*>(wb + (size_t)r * HD_ + c) = o;
}

// ---------------- GEMM: C[m][n] = sum_k A[m][k]*W[n][k] + bias[n] ----------------
template <int EPI>
__global__ __launch_bounds__(256, 2) void k_gemm(
    const unsigned short* __restrict__ A,   // [M][K] bf16
    const unsigned short* __restrict__ W,   // [Nt][K] bf16
    const float* __restrict__ bias,         // [Nt]
    unsigned short* __restrict__ Qo, unsigned short* __restrict__ Ko,
    unsigned short* __restrict__ Vo, float* __restrict__ Fo,
    int M, int Nt, int K)
{
  __shared__ unsigned short As[128 * 32];
  __shared__ unsigned short Bs[128 * 32];
  const int t = threadIdx.x;
  const int w = t >> 6, l = t & 63, lg = l >> 4, lr = l & 15;
  const int wm = w >> 1, wn = w & 1;
  const int row0 = blockIdx.x * 128, col0 = blockIdx.y * 128;

  f32x4 acc[4][4] = {};

  for (int k0 = 0; k0 < K; k0 += 32) {
#pragma unroll
    for (int c = 0; c < 2; ++c) {
      int ci = w * 2 + c;
      int eo = ci * 512 + l * 8;            // element offset within 128x32 tile
      int rr = eo >> 5, kk = eo & 31;
      gld16(A + (size_t)(row0 + rr) * K + k0 + kk, (unsigned short*)As + ci * 512);
      gld16(W + (size_t)(col0 + rr) * K + k0 + kk, (unsigned short*)Bs + ci * 512);
    }
    __syncthreads();
    bf16x8 af[4], bf[4];
#pragma unroll
    for (int m = 0; m < 4; ++m)
      af[m] = *reinterpret_cast<const bf16x8*>(&As[(wm * 64 + m * 16 + lr) * 32 + lg * 8]);
#pragma unroll
    for (int n = 0; n < 4; ++n)
      bf[n] = *reinterpret_cast<const bf16x8*>(&Bs[(wn * 64 + n * 16 + lr) * 32 + lg * 8]);
#pragma unroll
    for (int m = 0; m < 4; ++m)
#pragma unroll
      for (int n = 0; n < 4; ++n)
        acc[m][n] = __builtin_amdgcn_mfma_f32_16x16x32_bf16(af[m], bf[n], acc[m][n], 0, 0, 0);
    __syncthreads();
  }

#pragma unroll
  for (int m = 0; m < 4; ++m) {
#pragma unroll
    for (int n = 0; n < 4; ++n) {
      int col = col0 + wn * 64 + n * 16 + lr;
      float bb = bias[col];
#pragma unroll
      for (int rr = 0; rr < 4; ++rr) {
        int ro = row0 + wm * 64 + m * 16 + lg * 4 + rr;
        float val = acc[m][n][rr] + bb;
        if (EPI == 0) {
          int kind = col >> 10, hd = col & 1023, h = hd >> 6, d = hd & 63;
          int bi = ro >> 11, ni = ro & 2047;     // token -> (b, n)
          unsigned short bv = f2bf(val);
          size_t bh = (size_t)(bi * H_ + h);
          if (kind == 0)      Qo[(bh * N_ + ni) * D_ + d] = bv;
          else if (kind == 1) Ko[(bh * N_ + ni) * D_ + d] = bv;
          else                Vo[bh * (size_t)(D_ * N_) + (size_t)d * N_ + ni] = bv;
        } else {
          Fo[(size_t)ro * HD_ + col] = val;
        }
      }
    }
  }
}

// ---------------- flash attention ----------------
// Flat grid of 768 blocks: bh = blockIdx.x & 31 (same-head blocks land on the
// same XCD -> K/V L2-resident: 4 heads x 512KB = 2MB < 4MB), unit = blockIdx.x>>5
// indexes a heavy-first work table. q-tiles with q0>=1024 are split into two
// kv-chunks (balanced work, 2x parallelism); their unnormalized bf16 partials
// + (m,l) go to ws, merged by k_merge. 4 waves/block, each wave 32 q-rows,
// zero barriers, K/V fragments loaded directly from global (L2).
// V loads issued BEFORE next-K prefetch so PV's vmcnt wait excludes prefetch.
__global__ __launch_bounds__(256, 2) void k_attn(
    const unsigned short* __restrict__ Q,
    const unsigned short* __restrict__ Kg,
    const unsigned short* __restrict__ Vg,
    unsigned short* __restrict__ O,
    unsigned short* __restrict__ Pp,    // [bh][16][128][64] bf16 partial O~
    float* __restrict__ Pml)            // [bh][16][128][2]  (m, l)
{
  static const int u_qt[24] = {15,15,14,13,12,11,10,9,8,7,14,6,13,5,12,4,11,3,10,2,9,1,8,0};
  static const int u_t0[24] = { 0,16, 0, 0, 0, 0, 0,0,0,0,16,0,16,0,16,0,16,0,16,0,16,0,16,0};
  static const int u_ps[24] = {14,15,12,10, 8, 6, 4,2,0,-1,13,-1,11,-1,9,-1,7,-1,5,-1,3,-1,1,-1};

  __shared__ unsigned short Ps[4][32 * 64];   // per-wave P tile (XOR-swizzled)
  const int t = threadIdx.x;
  const int w = t >> 6, l = t & 63, lg = l >> 4, lr = l & 15;
  const int bh = blockIdx.x & 31;
  const int u  = blockIdx.x >> 5;
  const int qt = u_qt[u], t0 = u_t0[u], ps = u_ps[u];
  const int q0 = qt * 128;
  const int r0w = q0 + w * 32;                 // first q row owned by this wave
  const int rtop = r0w + 31;
  const bool splitc0 = (ps >= 0) && (t0 == 0);
  const int tend = splitc0 ? 16 : ((rtop >> 6) + 1);   // exclusive kv-tile end

  const unsigned short* Qb = Q  + (size_t)bh * (N_ * D_);
  const unsigned short* Kb = Kg + (size_t)bh * (N_ * D_);
  const unsigned short* Vb = Vg + (size_t)bh * (N_ * D_);   // [d][n]
  char* pw = (char*)&Ps[w][0];

  // Q A-fragments
  bf16x8 aq[2][2];
#pragma unroll
  for (int rg = 0; rg < 2; ++rg)
#pragma unroll
    for (int kk = 0; kk < 2; ++kk)
      aq[rg][kk] = *reinterpret_cast<const bf16x8*>(
          Qb + (size_t)(r0w + rg * 16 + lr) * D_ + kk * 32 + lg * 8);

  f32x4 oacc[2][4] = {};
  float mrun[2][4], lrun[2][4];
#pragma unroll
  for (int rg = 0; rg < 2; ++rg)
#pragma unroll
    for (int r = 0; r < 4; ++r) { mrun[rg][r] = -1e30f; lrun[rg][r] = 0.f; }

  // first K tile fragments
  bf16x8 kb[4][2];
#pragma unroll
  for (int ct = 0; ct < 4; ++ct)
#pragma unroll
    for (int kk = 0; kk < 2; ++kk)
      kb[ct][kk] = *reinterpret_cast<const bf16x8*>(
          Kb + (size_t)(t0 * 64 + ct * 16 + lr) * D_ + kk * 32 + lg * 8);

  for (int kt = t0; kt < tend; ++kt) {
    const int kv0 = kt * 64;
    // ---- S = Q K^T ----
    f32x4 s[2][4];
#pragma unroll
    for (int rg = 0; rg < 2; ++rg)
#pragma unroll
      for (int ct = 0; ct < 4; ++ct) {
        f32x4 z = {};
        z = __builtin_amdgcn_mfma_f32_16x16x32_bf16(aq[rg][0], kb[ct][0], z, 0, 0, 0);
        z = __builtin_amdgcn_mfma_f32_16x16x32_bf16(aq[rg][1], kb[ct][1], z, 0, 0, 0);
        s[rg][ct] = z;
      }

    // ---- V fragments for CURRENT tile: issued first so PV's vmcnt wait
    //      completes without draining the next-K prefetch ----
    bf16x8 vb[4][2];
#pragma unroll
    for (int dt = 0; dt < 4; ++dt)
#pragma unroll
      for (int kk = 0; kk < 2; ++kk)
        vb[dt][kk] = *reinterpret_cast<const bf16x8*>(
            Vb + (size_t)(dt * 16 + lr) * N_ + kv0 + kk * 32 + lg * 8);

    // ---- prefetch next K tile ----
    if (kt + 1 < tend) {
      const unsigned short* kp = Kb + (size_t)(kv0 + 64) * D_;
#pragma unroll
      for (int ct = 0; ct < 4; ++ct)
#pragma unroll
        for (int kk = 0; kk < 2; ++kk)
          kb[ct][kk] = *reinterpret_cast<const bf16x8*>(
              kp + (size_t)(ct * 16 + lr) * D_ + kk * 32 + lg * 8);
    }

    // ---- causal mask (only diagonal-intersecting tiles; never for split-c0) ----
    if (kv0 + 63 > r0w) {
#pragma unroll
      for (int rg = 0; rg < 2; ++rg)
#pragma unroll
        for (int ct = 0; ct < 4; ++ct)
#pragma unroll
          for (int r = 0; r < 4; ++r) {
            int col = kv0 + ct * 16 + lr;
            int row = r0w + rg * 16 + lg * 4 + r;
            if (col > row) s[rg][ct][r] = -1e30f;
          }
    }

    // ---- online softmax (exp2 domain) ----
#pragma unroll
    for (int rg = 0; rg < 2; ++rg) {
      float corr[4];
#pragma unroll
      for (int r = 0; r < 4; ++r) {
        float mx = fmaxf(fmaxf(s[rg][0][r], s[rg][1][r]), fmaxf(s[rg][2][r], s[rg][3][r]));
        mx = fmaxf(mx, __shfl_xor(mx, 1));
        mx = fmaxf(mx, __shfl_xor(mx, 2));
        mx = fmaxf(mx, __shfl_xor(mx, 4));
        mx = fmaxf(mx, __shfl_xor(mx, 8));
        float mnew = fmaxf(mrun[rg][r], mx);
        corr[r] = exp2f(mrun[rg][r] - mnew);
        float ps2 = 0.f;
#pragma unroll
        for (int ct = 0; ct < 4; ++ct) {
          float pv = exp2f(s[rg][ct][r] - mnew);
          s[rg][ct][r] = pv; ps2 += pv;
        }
        ps2 += __shfl_xor(ps2, 1);
        ps2 += __shfl_xor(ps2, 2);
        ps2 += __shfl_xor(ps2, 4);
        ps2 += __shfl_xor(ps2, 8);
        lrun[rg][r] = lrun[rg][r] * corr[r] + ps2;
        mrun[rg][r] = mnew;
      }
      // P -> per-wave LDS, XOR-swizzled (byte ^= (row&7)<<4)
#pragma unroll
      for (int ct = 0; ct < 4; ++ct)
#pragma unroll
        for (int r = 0; r < 4; ++r) {
          int row = rg * 16 + lg * 4 + r;
          int bo = (row * 128 + (ct * 16 + lr) * 2) ^ ((row & 7) << 4);
          *(unsigned short*)(pw + bo) = f2bf(s[rg][ct][r]);
        }
#pragma unroll
      for (int dt = 0; dt < 4; ++dt)
#pragma unroll
        for (int r = 0; r < 4; ++r)
          oacc[rg][dt][r] *= corr[r];
    }

    // ---- PV ----
#pragma unroll
    for (int rg = 0; rg < 2; ++rg) {
      bf16x8 pa[2];
#pragma unroll
      for (int kk = 0; kk < 2; ++kk) {
        int row = rg * 16 + lr;
        int bo = (row * 128 + (kk * 32 + lg * 8) * 2) ^ ((row & 7) << 4);
        pa[kk] = *reinterpret_cast<const bf16x8*>(pw + bo);
      }
#pragma unroll
      for (int dt = 0; dt < 4; ++dt) {
        oacc[rg][dt] = __builtin_amdgcn_mfma_f32_16x16x32_bf16(pa[0], vb[dt][0], oacc[rg][dt], 0, 0, 0);
        oacc[rg][dt] = __builtin_amdgcn_mfma_f32_16x16x32_bf16(pa[1], vb[dt][1], oacc[rg][dt], 0, 0, 0);
      }
    }
  }

  // ---- epilogue ----
  int bi = bh >> 4, h = bh & 15;
  if (ps < 0) {                    // direct: normalize and write [b][n][h][d]
#pragma unroll
    for (int rg = 0; rg < 2; ++rg)
#pragma unroll
      for (int dt = 0; dt < 4; ++dt)
#pragma unroll
        for (int r = 0; r < 4; ++r) {
          int qr = r0w + rg * 16 + lg * 4 + r;
          float val = oacc[rg][dt][r] / lrun[rg][r];
          O[((size_t)(bi * N_ + qr) * H_ + h) * D_ + dt * 16 + lr] = f2bf(val);
        }
  } else {                          // partial: unnormalized O~ + (m,l)
    unsigned short* pb = Pp + (size_t)(bh * 16 + ps) * (128 * 64);
    float* mb = Pml + (size_t)(bh * 16 + ps) * (128 * 2);
#pragma unroll
    for (int rg = 0; rg < 2; ++rg)
#pragma unroll
      for (int dt = 0; dt < 4; ++dt)
#pragma unroll
        for (int r = 0; r < 4; ++r) {
          int rloc = w * 32 + rg * 16 + lg * 4 + r;
          pb[rloc * 64 + dt * 16 + lr] = f2bf(oacc[rg][dt][r]);
        }
    if (lr == 0) {
#pragma unroll
      for (int rg = 0; rg < 2; ++rg)
#pragma unroll
        for (int r = 0; r < 4; ++r) {
          int rloc = w * 32 + rg * 16 + lg * 4 + r;
          mb[rloc * 2]     = mrun[rg][r];
          mb[rloc * 2 + 1] = lrun[rg][r];
        }
    }
  }
}

// ---------------- merge the two kv-chunk partials for q0>=1024 tiles ----------------
__global__ void k_merge(const unsigned short* __restrict__ Pp,
                        const float* __restrict__ Pml,
                        unsigned short* __restrict__ O) {
  int t = blockIdx.x * 256 + threadIdx.x;   // 262144 threads
  int dseg = t & 7;                          // 8 bf16 per thread
  int rloc = (t >> 3) & 127;
  int qt8 = (t >> 10) & 7;                   // qt - 8
  int bh  = t >> 13;
  size_t b0 = (size_t)(bh * 16 + qt8 * 2) * 128 + rloc;
  size_t b1 = b0 + 128;
  bf16x8 o0 = *reinterpret_cast<const bf16x8*>(Pp + b0 * 64 + dseg * 8);
  bf16x8 o1 = *reinterpret_cast<const bf16x8*>(Pp + b1 * 64 + dseg * 8);
  float m0 = Pml[b0 * 2], l0 = Pml[b0 * 2 + 1];
  float m1 = Pml[b1 * 2], l1 = Pml[b1 * 2 + 1];
  float m = fmaxf(m0, m1);
  float a0 = exp2f(m0 - m), a1 = exp2f(m1 - m);
  float inv = 1.0f / (l0 * a0 + l1 * a1);
  int n = (qt8 + 8) * 128 + rloc;
  int bi = bh >> 4, h = bh & 15;
  unsigned short* op = O + ((size_t)(bi * N_ + n) * H_ + h) * D_ + dseg * 8;
  bf16x8 res;
#pragma unroll
  for (int j = 0; j < 8; ++j)
    res[j] = (short)f2bf((bf2f(o0[j]) * a0 + bf2f(o1[j]) * a1) * inv);
  *reinterpret_cast<bf16x8*>(op) = res;
}

// ---------------- launch ----------------

extern "C" void kernel_launch(void* const* d_in, const int* in_sizes, int n_in,
                              void* d_out, int out_size, void* d_ws, size_t ws_size,
                              hipStream_t stream) {
  const float* x    = (const float*)d_in[0];
  const float* Wqkv = (const float*)d_in[1];
  const float* bqkv = (const float*)d_in[2];
  const float* Wout = (const float*)d_in[3];
  const float* bout = (const float*)d_in[4];
  float* out = (float*)d_out;

  char* ws = (char*)d_ws;
  unsigned short* xb  = (unsigned short*)ws; ws += (size_t)M_ * E_ * 2;       // 8 MB
  unsigned short* wqb = (unsigned short*)ws; ws += (size_t)NT_ * E_ * 2;      // 6 MB
  float*          bqr = (float*)ws;          ws += 16384;                     // 12 KB (+pad)
  unsigned short* wob = (unsigned short*)ws; ws += (size_t)E_ * HD_ * 2;      // 2 MB
  unsigned short* Qb  = (unsigned short*)ws; ws += (size_t)M_ * D_ * H_ * 2;  // 8 MB
  unsigned short* Kb  = (unsigned short*)ws; ws += (size_t)M_ * D_ * H_ * 2;  // 8 MB
  unsigned short* Vb  = (unsigned short*)ws; ws += (size_t)M_ * D_ * H_ * 2;  // 8 MB
  unsigned short* ao  = (unsigned short*)ws; ws += (size_t)M_ * HD_ * 2;      // 8 MB

  // attention partials ALIAS xb/wqb: both are dead once k_gemm<0> completes,
  // and the stream serializes gemm0 -> attn -> merge.
  unsigned short* Pp  = xb;            // 32*16*128*64 bf16 = 8 MB
  float*          Pml = (float*)wqb;   // 32*16*128*2  f32  = 512 KB

  k_cvt_x<<<(M_ * E_) / 4 / 256, 256, 0, stream>>>(x, xb);
  k_cvt_wqkv<<<NT_, 256, 0, stream>>>(Wqkv, bqkv, wqb, bqr);
  k_cvt_wout<<<E_, 256, 0, stream>>>(Wout, wob);

  k_gemm<0><<<dim3(M_ / 128, NT_ / 128), 256, 0, stream>>>(
      xb, wqb, bqr, Qb, Kb, Vb, nullptr, M_, NT_, E_);

  k_attn<<<768, 256, 0, stream>>>(Qb, Kb, Vb, ao, Pp, Pml);
  k_merge<<<1024, 256, 0, stream>>>(Pp, Pml, ao);

  k_gemm<1><<<dim3(M_ / 128, HD_ / 128), 256, 0, stream>>>(
      ao, wob, bout, nullptr, nullptr, nullptr, out, M_, HD_, E_);
}

// Round 4
// 156.742 us; speedup vs baseline: 1.4140x; 1.0086x over previous
//
#include <hip/hip_runtime.h>
#include <hip/hip_bf16.h>

// Problem constants (B,N,E,H,D) = (2,2048,1024,16,64)
#define B_ 2
#define N_ 2048
#define E_ 1024
#define H_ 16
#define D_ 64
#define M_ 4096      // B*N
#define HD_ 1024     // H*D
#define NT_ 3072     // 3*H*D

using f32x4  = __attribute__((ext_vector_type(4))) float;
using f32x16 = __attribute__((ext_vector_type(16))) float;
using bf16x8 = __attribute__((ext_vector_type(8))) short;

static __device__ __forceinline__ unsigned short f2bf(float f) {
  union { float f; unsigned u; } v; v.f = f;
  unsigned r = v.u + 0x7FFF + ((v.u >> 16) & 1);   // RNE
  return (unsigned short)(r >> 16);
}
static __device__ __forceinline__ float bf2f(short s) {
  union { unsigned u; float f; } v; v.u = ((unsigned)(unsigned short)s) << 16; return v.f;
}

// async global->LDS, 16B per lane. LDS dest = wave-uniform base + lane*16.
static __device__ __forceinline__ void gld16(const void* g, void* l) {
  __builtin_amdgcn_global_load_lds(
      (const __attribute__((address_space(1))) unsigned int*)g,
      (__attribute__((address_space(3))) unsigned int*)l, 16, 0, 0);
}

// v_cvt_pk_bf16_f32: D[15:0]=bf16(lo), D[31:16]=bf16(hi)
static __device__ __forceinline__ unsigned cvtpk(float lo, float hi) {
  unsigned r;
  asm("v_cvt_pk_bf16_f32 %0, %1, %2" : "=v"(r) : "v"(lo), "v"(hi));
  return r;
}
// v_permlane32_swap_b32: a.hi-lanes <-> b.lo-lanes
static __device__ __forceinline__ void pl32swap(unsigned& a, unsigned& b) {
  asm("v_permlane32_swap_b32 %0, %1" : "+v"(a), "+v"(b));
}

// ---------------- conversion kernels ----------------

__global__ void k_cvt_x(const float* __restrict__ x, unsigned short* __restrict__ xb) {
  int t = blockIdx.x * 256 + threadIdx.x;          // one float4 per thread
  float4 v = reinterpret_cast<const float4*>(x)[t];
  ushort4 o;
  o.x = f2bf(v.x); o.y = f2bf(v.y); o.z = f2bf(v.z); o.w = f2bf(v.w);
  reinterpret_cast<ushort4*>(xb)[t] = o;
}

// Wqkv rows are interleaved (h, d, kind): rin = h*192 + d*3 + kind.
// Output row r = kind*1024 + h*64 + d.
// Q rows (kind==0) pre-scaled by (1/8)*log2(e) so attention can use exp2.
__global__ void k_cvt_wqkv(const float* __restrict__ w, const float* __restrict__ bsrc,
                           unsigned short* __restrict__ wb, float* __restrict__ br) {
  int t = blockIdx.x * 256 + threadIdx.x;
  int r = t >> 8;                 // 0..3071
  int c = (t & 255) * 4;
  int kind = r >> 10, hd = r & 1023;
  int h = hd >> 6, d = hd & 63;
  int rin = h * 192 + d * 3 + kind;
  float s = (kind == 0) ? 0.125f * 1.4426950408889634f : 1.0f;
  float4 v = *reinterpret_cast<const float4*>(w + (size_t)rin * E_ + c);
  ushort4 o;
  o.x = f2bf(v.x * s); o.y = f2bf(v.y * s); o.z = f2bf(v.z * s); o.w = f2bf(v.w * s);
  *reinterpret_cast<ushort4*>(wb + (size_t)r * E_ + c) = o;
  if (c == 0) br[r] = bsrc[rin] * s;
}

__global__ void k_cvt_wout(const float* __restrict__ w, unsigned short* __restrict__ wb) {
  int t = blockIdx.x * 256 + threadIdx.x;
  int r = t >> 8;
  int c = (t & 255) * 4;
  float4 v = *reinterpret_cast<const float4*>(w + (size_t)r * HD_ + c);
  ushort4 o;
  o.x = f2bf(v.x); o.y = f2bf(v.y); o.z = f2bf(v.z); o.w = f2bf(v.w);
  *reinterpret_cast<ushort4*>(wb + (size_t)r * HD_ + c) = o;
}

// ---------------- GEMM: C[m][n] = sum_k A[m][k]*W[n][k] + bias[n] ----------------
template <int EPI>
__global__ __launch_bounds__(256, 2) void k_gemm(
    const unsigned short* __restrict__ A,   // [M][K] bf16
    const unsigned short* __restrict__ W,   // [Nt][K] bf16
    const float* __restrict__ bias,         // [Nt]
    unsigned short* __restrict__ Qo, unsigned short* __restrict__ Ko,
    unsigned short* __restrict__ Vo, float* __restrict__ Fo,
    int M, int Nt, int K)
{
  __shared__ unsigned short As[128 * 32];
  __shared__ unsigned short Bs[128 * 32];
  const int t = threadIdx.x;
  const int w = t >> 6, l = t & 63, lg = l >> 4, lr = l & 15;
  const int wm = w >> 1, wn = w & 1;
  const int row0 = blockIdx.x * 128, col0 = blockIdx.y * 128;

  f32x4 acc[4][4] = {};

  for (int k0 = 0; k0 < K; k0 += 32) {
#pragma unroll
    for (int c = 0; c < 2; ++c) {
      int ci = w * 2 + c;
      int eo = ci * 512 + l * 8;            // element offset within 128x32 tile
      int rr = eo >> 5, kk = eo & 31;
      gld16(A + (size_t)(row0 + rr) * K + k0 + kk, (unsigned short*)As + ci * 512);
      gld16(W + (size_t)(col0 + rr) * K + k0 + kk, (unsigned short*)Bs + ci * 512);
    }
    __syncthreads();
    bf16x8 af[4], bf[4];
#pragma unroll
    for (int m = 0; m < 4; ++m)
      af[m] = *reinterpret_cast<const bf16x8*>(&As[(wm * 64 + m * 16 + lr) * 32 + lg * 8]);
#pragma unroll
    for (int n = 0; n < 4; ++n)
      bf[n] = *reinterpret_cast<const bf16x8*>(&Bs[(wn * 64 + n * 16 + lr) * 32 + lg * 8]);
#pragma unroll
    for (int m = 0; m < 4; ++m)
#pragma unroll
      for (int n = 0; n < 4; ++n)
        acc[m][n] = __builtin_amdgcn_mfma_f32_16x16x32_bf16(af[m], bf[n], acc[m][n], 0, 0, 0);
    __syncthreads();
  }

#pragma unroll
  for (int m = 0; m < 4; ++m) {
#pragma unroll
    for (int n = 0; n < 4; ++n) {
      int col = col0 + wn * 64 + n * 16 + lr;
      float bb = bias[col];
#pragma unroll
      for (int rr = 0; rr < 4; ++rr) {
        int ro = row0 + wm * 64 + m * 16 + lg * 4 + rr;
        float val = acc[m][n][rr] + bb;
        if (EPI == 0) {
          int kind = col >> 10, hd = col & 1023, h = hd >> 6, d = hd & 63;
          int bi = ro >> 11, ni = ro & 2047;     // token -> (b, n)
          unsigned short bv = f2bf(val);
          size_t bh = (size_t)(bi * H_ + h);
          if (kind == 0)      Qo[(bh * N_ + ni) * D_ + d] = bv;
          else if (kind == 1) Ko[(bh * N_ + ni) * D_ + d] = bv;
          else                Vo[bh * (size_t)(D_ * N_) + (size_t)d * N_ + ni] = bv;
        } else {
          Fo[(size_t)ro * HD_ + col] = val;
        }
      }
    }
  }
}

// ---------------- flash attention (swapped 32x32 MFMA, zero LDS) ----------------
// S^T = K·Q^T via mfma_f32_32x32x16_bf16: lane owns ONE q row (q = lane&31),
// 32 P values in-register. Softmax: 31 in-lane ops + 1 shfl_xor(32).
// P -> PV A-frags fully in-register: 16 v_cvt_pk_bf16_f32 + 8 v_permlane32_swap.
// Defer-max (THR=8) skips O-rescale on most tiles. Zero barriers, zero LDS.
// Work table balanced so each CU's 3 blocks sum to 34 kv-tiles.
__global__ __launch_bounds__(256, 2) void k_attn(
    const unsigned short* __restrict__ Q,
    const unsigned short* __restrict__ Kg,
    const unsigned short* __restrict__ Vg,
    unsigned short* __restrict__ O,
    unsigned short* __restrict__ Pp,    // [bh][16][128][64] bf16 partial O~
    float* __restrict__ Pml)            // [bh][16][128][2]  (m, l)
{
  // columns (a, a+8, a+16) sum to 34 tiles: {16,16,2}x2 {16,14,4}x2 {16,12,6}x2 {16,10,8}x2
  static const int u_qt[24] = {15,15,14,13,12,11,10, 9,   8, 7,14, 6,13, 5,12, 4,   8, 0, 9, 1,10, 2,11, 3};
  static const int u_t0[24] = { 0,16, 0, 0, 0, 0, 0, 0,   0, 0,16, 0,16, 0,16, 0,  16, 0,16, 0,16, 0,16, 0};
  static const int u_ps[24] = {14,15,12,10, 8, 6, 4, 2,   0,-1,13,-1,11,-1, 9,-1,   1,-1, 3,-1, 5,-1, 7,-1};

  const int t = threadIdx.x;
  const int w = t >> 6, l = t & 63;
  const int lq = l & 31;          // q-col / kv-row / d-col lane index
  const int hi = l >> 5;          // half-wave
  const int bh = blockIdx.x & 31; // same-head blocks -> same XCD (L2-resident K/V)
  const int u  = blockIdx.x >> 5;
  const int qt = u_qt[u], t0 = u_t0[u], ps = u_ps[u];
  const int q0 = qt * 128;
  const int r0w = q0 + w * 32;                 // first q row owned by this wave
  const int rtop = r0w + 31;
  const int tend = ((ps >= 0) && (t0 == 0)) ? 16 : ((rtop >> 6) + 1);

  const unsigned short* Qb = Q  + (size_t)bh * (N_ * D_);
  const unsigned short* Kb = Kg + (size_t)bh * (N_ * D_);
  const unsigned short* Vb = Vg + (size_t)bh * (N_ * D_);   // [d][n]

  // Q B-fragments: lane holds q-col = lq, k = ks*16 + hi*8 + e
  bf16x8 qf[4];
#pragma unroll
  for (int ks = 0; ks < 4; ++ks)
    qf[ks] = *reinterpret_cast<const bf16x8*>(
        Qb + (size_t)(r0w + lq) * D_ + ks * 16 + hi * 8);

  f32x16 oacc[2] = {};            // dt = d/32; C: d = dt*32+lq, q_local = (r&3)+8*(r>>2)+4*hi
  float mrun = -1e30f, lrun = 0.f;

  // K A-frags for first tile: lane holds kv-row = ct*32+lq, k = ks*16 + hi*8 + e
  bf16x8 kf[2][4];
#pragma unroll
  for (int ct = 0; ct < 2; ++ct)
#pragma unroll
    for (int ks = 0; ks < 4; ++ks)
      kf[ct][ks] = *reinterpret_cast<const bf16x8*>(
          Kb + (size_t)(t0 * 64 + ct * 32 + lq) * D_ + ks * 16 + hi * 8);

  for (int kt = t0; kt < tend; ++kt) {
    const int kv0 = kt * 64;

    // ---- S^T = K Q^T : 8 mfma_32x32x16 ----
    f32x16 sct[2];
#pragma unroll
    for (int ct = 0; ct < 2; ++ct) {
      f32x16 z = {};
#pragma unroll
      for (int ks = 0; ks < 4; ++ks)
        z = __builtin_amdgcn_mfma_f32_32x32x16_bf16(kf[ct][ks], qf[ks], z, 0, 0, 0);
      sct[ct] = z;
    }

    // ---- V B-frags for current tile (issued before K prefetch) ----
    bf16x8 vf[2][4];
#pragma unroll
    for (int dt = 0; dt < 2; ++dt)
#pragma unroll
      for (int j = 0; j < 4; ++j)
        vf[dt][j] = *reinterpret_cast<const bf16x8*>(
            Vb + (size_t)(dt * 32 + lq) * N_ + kv0 + j * 16 + hi * 8);

    // ---- prefetch next K tile ----
    if (kt + 1 < tend) {
      const unsigned short* kp = Kb + (size_t)(kv0 + 64) * D_;
#pragma unroll
      for (int ct = 0; ct < 2; ++ct)
#pragma unroll
        for (int ks = 0; ks < 4; ++ks)
          kf[ct][ks] = *reinterpret_cast<const bf16x8*>(
              kp + (size_t)(ct * 32 + lq) * D_ + ks * 16 + hi * 8);
    }

    // ---- causal mask (diag tile only) ----
    if (kv0 + 63 > r0w) {
      int qrow = r0w + lq;
#pragma unroll
      for (int ct = 0; ct < 2; ++ct)
#pragma unroll
        for (int r = 0; r < 16; ++r) {
          int kv = kv0 + ct * 32 + (r & 3) + 8 * (r >> 2) + 4 * hi;
          if (kv > qrow) sct[ct][r] = -1e30f;
        }
    }

    // ---- online softmax, defer-max (THR=8) ----
    float pm = sct[0][0];
#pragma unroll
    for (int r = 1; r < 16; ++r) pm = fmaxf(pm, sct[0][r]);
#pragma unroll
    for (int r = 0; r < 16; ++r) pm = fmaxf(pm, sct[1][r]);
    pm = fmaxf(pm, __shfl_xor(pm, 32));
    if (__any(pm > mrun + 8.f)) {
      float mnew = fmaxf(mrun, pm);
      float corr = exp2f(mrun - mnew);
      mrun = mnew; lrun *= corr;
      float co[16];
#pragma unroll
      for (int r = 0; r < 16; ++r)
        co[r] = __shfl(corr, (r & 3) + 8 * (r >> 2) + 4 * hi);
#pragma unroll
      for (int dt = 0; dt < 2; ++dt)
#pragma unroll
        for (int r = 0; r < 16; ++r) oacc[dt][r] *= co[r];
    }
    float ts = 0.f;
#pragma unroll
    for (int ct = 0; ct < 2; ++ct)
#pragma unroll
      for (int r = 0; r < 16; ++r) {
        float p = exp2f(sct[ct][r] - mrun);
        sct[ct][r] = p; ts += p;
      }
    ts += __shfl_xor(ts, 32);
    lrun += ts;

    // ---- P -> A-frags in-register: cvt_pk pairs + permlane32_swap ----
    bf16x8 paf[4];
#pragma unroll
    for (int ct = 0; ct < 2; ++ct) {
      unsigned u0 = cvtpk(sct[ct][0],  sct[ct][1]);
      unsigned u1 = cvtpk(sct[ct][2],  sct[ct][3]);
      unsigned u2 = cvtpk(sct[ct][4],  sct[ct][5]);
      unsigned u3 = cvtpk(sct[ct][6],  sct[ct][7]);
      unsigned u4 = cvtpk(sct[ct][8],  sct[ct][9]);
      unsigned u5 = cvtpk(sct[ct][10], sct[ct][11]);
      unsigned u6 = cvtpk(sct[ct][12], sct[ct][13]);
      unsigned u7 = cvtpk(sct[ct][14], sct[ct][15]);
      pl32swap(u0, u2); pl32swap(u1, u3);   // step0: kv ct*32 + 0..15
      pl32swap(u4, u6); pl32swap(u5, u7);   // step1: kv ct*32 + 16..31
      union { unsigned uu[4]; bf16x8 v; } c0, c1;
      c0.uu[0] = u0; c0.uu[1] = u1; c0.uu[2] = u2; c0.uu[3] = u3;
      c1.uu[0] = u4; c1.uu[1] = u5; c1.uu[2] = u6; c1.uu[3] = u7;
      paf[ct * 2]     = c0.v;
      paf[ct * 2 + 1] = c1.v;
    }

    // ---- PV: 8 mfma_32x32x16 ----
#pragma unroll
    for (int dt = 0; dt < 2; ++dt)
#pragma unroll
      for (int j = 0; j < 4; ++j)
        oacc[dt] = __builtin_amdgcn_mfma_f32_32x32x16_bf16(paf[j], vf[dt][j], oacc[dt], 0, 0, 0);
  }

  // ---- epilogue ----
  int bi = bh >> 4, h = bh & 15;
  if (ps < 0) {                    // direct: normalize, write [b][n][h][d]
    float inv = 1.0f / lrun;
    float iv[16];
#pragma unroll
    for (int r = 0; r < 16; ++r)
      iv[r] = __shfl(inv, (r & 3) + 8 * (r >> 2) + 4 * hi);
#pragma unroll
    for (int dt = 0; dt < 2; ++dt)
#pragma unroll
      for (int r = 0; r < 16; ++r) {
        int qr = r0w + (r & 3) + 8 * (r >> 2) + 4 * hi;
        int d = dt * 32 + lq;
        O[((size_t)(bi * N_ + qr) * H_ + h) * D_ + d] = f2bf(oacc[dt][r] * iv[r]);
      }
  } else {                          // partial: unnormalized O~ + (m,l)
    unsigned short* pb = Pp + (size_t)(bh * 16 + ps) * (128 * 64);
    float* mb = Pml + (size_t)(bh * 16 + ps) * (128 * 2);
#pragma unroll
    for (int dt = 0; dt < 2; ++dt)
#pragma unroll
      for (int r = 0; r < 16; ++r) {
        int rloc = w * 32 + (r & 3) + 8 * (r >> 2) + 4 * hi;
        pb[rloc * 64 + dt * 32 + lq] = f2bf(oacc[dt][r]);
      }
    if (l < 32) {
      int rloc = w * 32 + l;
      mb[rloc * 2]     = mrun;
      mb[rloc * 2 + 1] = lrun;
    }
  }
}

// ---------------- merge the two kv-chunk partials for q0>=1024 tiles ----------------
__global__ void k_merge(const unsigned short* __restrict__ Pp,
                        const float* __restrict__ Pml,
                        unsigned short* __restrict__ O) {
  int t = blockIdx.x * 256 + threadIdx.x;   // 262144 threads
  int dseg = t & 7;                          // 8 bf16 per thread
  int rloc = (t >> 3) & 127;
  int qt8 = (t >> 10) & 7;                   // qt - 8
  int bh  = t >> 13;
  size_t b0 = (size_t)(bh * 16 + qt8 * 2) * 128 + rloc;
  size_t b1 = b0 + 128;
  bf16x8 o0 = *reinterpret_cast<const bf16x8*>(Pp + b0 * 64 + dseg * 8);
  bf16x8 o1 = *reinterpret_cast<const bf16x8*>(Pp + b1 * 64 + dseg * 8);
  float m0 = Pml[b0 * 2], l0 = Pml[b0 * 2 + 1];
  float m1 = Pml[b1 * 2], l1 = Pml[b1 * 2 + 1];
  float m = fmaxf(m0, m1);
  float a0 = exp2f(m0 - m), a1 = exp2f(m1 - m);
  float inv = 1.0f / (l0 * a0 + l1 * a1);
  int n = (qt8 + 8) * 128 + rloc;
  int bi = bh >> 4, h = bh & 15;
  unsigned short* op = O + ((size_t)(bi * N_ + n) * H_ + h) * D_ + dseg * 8;
  bf16x8 res;
#pragma unroll
  for (int j = 0; j < 8; ++j)
    res[j] = (short)f2bf((bf2f(o0[j]) * a0 + bf2f(o1[j]) * a1) * inv);
  *reinterpret_cast<bf16x8*>(op) = res;
}

// ---------------- launch ----------------

extern "C" void kernel_launch(void* const* d_in, const int* in_sizes, int n_in,
                              void* d_out, int out_size, void* d_ws, size_t ws_size,
                              hipStream_t stream) {
  const float* x    = (const float*)d_in[0];
  const float* Wqkv = (const float*)d_in[1];
  const float* bqkv = (const float*)d_in[2];
  const float* Wout = (const float*)d_in[3];
  const float* bout = (const float*)d_in[4];
  float* out = (float*)d_out;

  char* ws = (char*)d_ws;
  unsigned short* xb  = (unsigned short*)ws; ws += (size_t)M_ * E_ * 2;       // 8 MB
  unsigned short* wqb = (unsigned short*)ws; ws += (size_t)NT_ * E_ * 2;      // 6 MB
  float*          bqr = (float*)ws;          ws += 16384;                     // 12 KB (+pad)
  unsigned short* wob = (unsigned short*)ws; ws += (size_t)E_ * HD_ * 2;      // 2 MB
  unsigned short* Qb  = (unsigned short*)ws; ws += (size_t)M_ * D_ * H_ * 2;  // 8 MB
  unsigned short* Kb  = (unsigned short*)ws; ws += (size_t)M_ * D_ * H_ * 2;  // 8 MB
  unsigned short* Vb  = (unsigned short*)ws; ws += (size_t)M_ * D_ * H_ * 2;  // 8 MB
  unsigned short* ao  = (unsigned short*)ws; ws += (size_t)M_ * HD_ * 2;      // 8 MB

  // attention partials ALIAS xb/wqb: both are dead once k_gemm<0> completes,
  // and the stream serializes gemm0 -> attn -> merge.
  unsigned short* Pp  = xb;            // 32*16*128*64 bf16 = 8 MB
  float*          Pml = (float*)wqb;   // 32*16*128*2  f32  = 512 KB

  k_cvt_x<<<(M_ * E_) / 4 / 256, 256, 0, stream>>>(x, xb);
  k_cvt_wqkv<<<NT_, 256, 0, stream>>>(Wqkv, bqkv, wqb, bqr);
  k_cvt_wout<<<E_, 256, 0, stream>>>(Wout, wob);

  k_gemm<0><<<dim3(M_ / 128, NT_ / 128), 256, 0, stream>>>(
      xb, wqb, bqr, Qb, Kb, Vb, nullptr, M_, NT_, E_);

  k_attn<<<768, 256, 0, stream>>>(Qb, Kb, Vb, ao, Pp, Pml);
  k_merge<<<1024, 256, 0, stream>>>(Pp, Pml, ao);

  k_gemm<1><<<dim3(M_ / 128, HD_ / 128), 256, 0, stream>>>(
      ao, wob, bout, nullptr, nullptr, nullptr, out, M_, HD_, E_);
}